// Round 4
// baseline (2714.945 us; speedup 1.0000x reference)
//
#include <hip/hip_runtime.h>
#include <hip/hip_bf16.h>
#include <math.h>

typedef __bf16 bf16_t;
typedef __bf16 bf16x8 __attribute__((ext_vector_type(8)));
typedef _Float16 f16x8 __attribute__((ext_vector_type(8)));
typedef float  floatx4 __attribute__((ext_vector_type(4)));

constexpr int T_TOK = 4096;
constexpr int HID   = 2048;
constexpr int NH    = 16;
constexpr int DH    = 128;   // head dim
constexpr int CH    = 2048;  // NH*DH

// ---------------- cast fp32 -> bf16 (row-major preserved) ----------------
__global__ __launch_bounds__(256) void cast_to_bf16(const float* __restrict__ in,
                                                    bf16_t* __restrict__ out, int n) {
  int i = (blockIdx.x * 256 + threadIdx.x) * 8;
  if (i >= n) return;
  float4 a = *(const float4*)(in + i);
  float4 b = *(const float4*)(in + i + 4);
  bf16x8 o;
  o[0]=(bf16_t)a.x; o[1]=(bf16_t)a.y; o[2]=(bf16_t)a.z; o[3]=(bf16_t)a.w;
  o[4]=(bf16_t)b.x; o[5]=(bf16_t)b.y; o[6]=(bf16_t)b.z; o[7]=(bf16_t)b.w;
  *(bf16x8*)(out + i) = o;
}

// ---------------- transpose + cast: in fp32 [R,C] -> out bf16 [C,R] ----------------
__global__ __launch_bounds__(256) void transpose_cast(const float* __restrict__ in,
                                                      bf16_t* __restrict__ out, int R, int C) {
  __shared__ float tile[32][33];
  int tx = threadIdx.x & 31;
  int ty = threadIdx.x >> 5;  // 0..7
  int r0 = blockIdx.x * 32;
  int c0 = blockIdx.y * 32;
#pragma unroll
  for (int i = 0; i < 4; i++) {
    int r = ty + i * 8;
    float v = 0.f;
    if (r0 + r < R && c0 + tx < C) v = in[(size_t)(r0 + r) * C + (c0 + tx)];
    tile[r][tx] = v;
  }
  __syncthreads();
#pragma unroll
  for (int i = 0; i < 4; i++) {
    int cr = ty + i * 8;
    if (c0 + cr < C && r0 + tx < R)
      out[(size_t)(c0 + cr) * R + (r0 + tx)] = (bf16_t)tile[tx][cr];
  }
}

// ---------------- bf16 MFMA GEMM: C[M,N] = A[M,K] * Bt[N,K]^T ----------------
template<bool OUT_BF16>
__global__ __launch_bounds__(256) void gemm_bf16(
    const bf16_t* __restrict__ A, int lda,
    const bf16_t* __restrict__ Bt, int ldb,
    void* __restrict__ Cv, int ldc, int M, int N, int K) {
  __shared__ bf16_t sA[128][40];
  __shared__ bf16_t sB[128][40];
  const int tid  = threadIdx.x;
  const int bm0  = blockIdx.x * 128;
  const int bn0  = blockIdx.y * 128;
  const int wave = tid >> 6;
  const int lane = tid & 63;
  const int wm   = (wave & 1) * 64;
  const int wn   = (wave >> 1) * 64;
  const int fm   = lane & 15;
  const int kq   = lane >> 4;

  floatx4 acc[4][4];
#pragma unroll
  for (int mi = 0; mi < 4; mi++)
#pragma unroll
    for (int ni = 0; ni < 4; ni++)
      acc[mi][ni] = (floatx4){0.f, 0.f, 0.f, 0.f};

  const int sr = tid >> 2;
  const int sk = (tid & 3) * 8;
  const bool bval0 = (bn0 + sr) < N;
  const bool bval1 = (bn0 + sr + 64) < N;
  const bf16_t* Ag0 = A + (size_t)(bm0 + sr) * lda + sk;
  const bf16_t* Ag1 = Ag0 + (size_t)64 * lda;
  const bf16_t* Bg0 = Bt + (size_t)(bn0 + sr) * ldb + sk;
  const bf16_t* Bg1 = Bg0 + (size_t)64 * ldb;

  for (int k0 = 0; k0 < K; k0 += 32) {
    float4 a0 = *(const float4*)(Ag0 + k0);
    float4 a1 = *(const float4*)(Ag1 + k0);
    float4 b0 = bval0 ? *(const float4*)(Bg0 + k0) : make_float4(0.f, 0.f, 0.f, 0.f);
    float4 b1 = bval1 ? *(const float4*)(Bg1 + k0) : make_float4(0.f, 0.f, 0.f, 0.f);
    __syncthreads();
    *(float4*)(&sA[sr][sk])      = a0;
    *(float4*)(&sA[sr + 64][sk]) = a1;
    *(float4*)(&sB[sr][sk])      = b0;
    *(float4*)(&sB[sr + 64][sk]) = b1;
    __syncthreads();
    bf16x8 afr[4], bfr[4];
#pragma unroll
    for (int i = 0; i < 4; i++) {
      afr[i] = *(const bf16x8*)(&sA[wm + i * 16 + fm][kq * 8]);
      bfr[i] = *(const bf16x8*)(&sB[wn + i * 16 + fm][kq * 8]);
    }
#pragma unroll
    for (int mi = 0; mi < 4; mi++)
#pragma unroll
      for (int ni = 0; ni < 4; ni++)
        acc[mi][ni] = __builtin_amdgcn_mfma_f32_16x16x32_bf16(afr[mi], bfr[ni], acc[mi][ni], 0, 0, 0);
  }

  const int rr = (lane >> 4) * 4;
#pragma unroll
  for (int mi = 0; mi < 4; mi++) {
#pragma unroll
    for (int r = 0; r < 4; r++) {
      const int row = bm0 + wm + mi * 16 + rr + r;
#pragma unroll
      for (int ni = 0; ni < 4; ni++) {
        const int col = bn0 + wn + ni * 16 + fm;
        if (col < N) {
          if constexpr (OUT_BF16)
            ((bf16_t*)Cv)[(size_t)row * ldc + col] = (bf16_t)acc[mi][ni][r];
          else
            ((float*)Cv)[(size_t)row * ldc + col] = acc[mi][ni][r];
        }
      }
    }
  }
}

// ---------------- conv + silu (+ l2norm) : raw bf16 [T,CH] -> out bf16 [T,CH] ----------------
template<bool L2NORM>
__global__ __launch_bounds__(256) void conv_silu(
    const bf16_t* __restrict__ raw, const float* __restrict__ wconv,
    bf16_t* __restrict__ out) {
  const int t   = blockIdx.x;
  const int tid = threadIdx.x;
  const int c0  = tid * 8;

  float w[8][4];
#pragma unroll
  for (int j = 0; j < 8; j++) {
    float4 t0 = *(const float4*)(wconv + (size_t)(c0 + j) * 4);
    w[j][0] = t0.x; w[j][1] = t0.y; w[j][2] = t0.z; w[j][3] = t0.w;
  }
  float a[8] = {};
#pragma unroll
  for (int i = 0; i < 4; i++) {
    int tr = t - 3 + i;
    if (tr < 0) continue;
    bf16x8 xr = *(const bf16x8*)(raw + (size_t)tr * CH + c0);
#pragma unroll
    for (int j = 0; j < 8; j++) a[j] += w[j][i] * (float)xr[j];
  }
  float s = 0.f;
#pragma unroll
  for (int j = 0; j < 8; j++) {
    a[j] = a[j] / (1.f + expf(-a[j]));  // silu
    s += a[j] * a[j];
  }
  float rs = 1.f;
  if constexpr (L2NORM) {
#pragma unroll
    for (int m = 1; m < 16; m <<= 1) s += __shfl_xor(s, m);
    rs = rsqrtf(s + 1e-6f);
  }
  bf16x8 r;
#pragma unroll
  for (int j = 0; j < 8; j++) r[j] = (bf16_t)(a[j] * rs);
  *(bf16x8*)(out + (size_t)t * CH + c0) = r;
}

// ---------------- gamma (f_pre -> fp16 gamma) + beta sigmoid (in-place) ----------------
__global__ __launch_bounds__(256) void gamma_beta(
    const float* __restrict__ f_pre, const float* __restrict__ dt_bias,
    const float* __restrict__ A_log, _Float16* __restrict__ gam_out,
    float* __restrict__ beta_io) {
  const int t   = blockIdx.x;
  const int tid = threadIdx.x;
  const int c0  = tid * 8;
  const int h   = c0 >> 7;
  const float a_h = expf(A_log[h]);
  const size_t o0 = (size_t)t * CH + c0;
  float fv[8], db[8];
  { float4 f0 = *(const float4*)(f_pre + o0);   float4 f1 = *(const float4*)(f_pre + o0 + 4);
    fv[0]=f0.x; fv[1]=f0.y; fv[2]=f0.z; fv[3]=f0.w; fv[4]=f1.x; fv[5]=f1.y; fv[6]=f1.z; fv[7]=f1.w;
    float4 d0 = *(const float4*)(dt_bias + c0); float4 d1 = *(const float4*)(dt_bias + c0 + 4);
    db[0]=d0.x; db[1]=d0.y; db[2]=d0.z; db[3]=d0.w; db[4]=d1.x; db[5]=d1.y; db[6]=d1.z; db[7]=d1.w; }
  f16x8 og;
#pragma unroll
  for (int j = 0; j < 8; j++) {
    float f = fv[j] + db[j];
    float sp = (f > 20.f) ? f : log1pf(expf(f));
    og[j] = (_Float16)expf(-a_h * sp);
  }
  *(f16x8*)(gam_out + o0) = og;
  if (tid < NH) {
    float b = beta_io[(size_t)t * NH + tid];
    beta_io[(size_t)t * NH + tid] = 1.f / (1.f + expf(-b));
  }
}

// ---------------- sequential scan ----------------
// 256 blocks = (head, 8-col group); 64 threads = 1 wave per block -> 1 wave/CU,
// sole owner of the CU's DS pipe. 8 lanes per column (16 k-states each).
// Per chunk of TC=16 steps: cooperative bulk load into double-buffered LDS.
// gamma staged as fp16 (halves DS traffic); k/q/v bf16.
constexpr int TC   = 16;
constexpr int NCHK = T_TOK / TC;

struct __align__(16) StepIn { float g[16], k[16], q[16]; float v, b; };
struct StageR { uint4 g[4], k[4], q[4]; uint4 v; float b; };

__device__ __forceinline__ void dostep(float S[16], const StepIn& in, int kp_lane,
                                       float* op, int t) {
  float e0 = 0.f, e1 = 0.f, e2 = 0.f, e3 = 0.f;
#pragma unroll
  for (int j = 0; j < 4; j++) {
    S[j]      *= in.g[j];      e0 = fmaf(S[j],      in.k[j],      e0);
    S[j + 4]  *= in.g[j + 4];  e1 = fmaf(S[j + 4],  in.k[j + 4],  e1);
    S[j + 8]  *= in.g[j + 8];  e2 = fmaf(S[j + 8],  in.k[j + 8],  e2);
    S[j + 12] *= in.g[j + 12]; e3 = fmaf(S[j + 12], in.k[j + 12], e3);
  }
  float err = (e0 + e1) + (e2 + e3);
  err += __shfl_xor(err, 1); err += __shfl_xor(err, 2); err += __shfl_xor(err, 4);
  const float dv = in.b * (in.v - err);
  float o0 = 0.f, o1 = 0.f, o2 = 0.f, o3 = 0.f;
#pragma unroll
  for (int j = 0; j < 4; j++) {
    S[j]      = fmaf(in.k[j],      dv, S[j]);      o0 = fmaf(S[j],      in.q[j],      o0);
    S[j + 4]  = fmaf(in.k[j + 4],  dv, S[j + 4]);  o1 = fmaf(S[j + 4],  in.q[j + 4],  o1);
    S[j + 8]  = fmaf(in.k[j + 8],  dv, S[j + 8]);  o2 = fmaf(S[j + 8],  in.q[j + 8],  o2);
    S[j + 12] = fmaf(in.k[j + 12], dv, S[j + 12]); o3 = fmaf(S[j + 12], in.q[j + 12], o3);
  }
  float os = (o0 + o1) + (o2 + o3);
  os += __shfl_xor(os, 1); os += __shfl_xor(os, 2); os += __shfl_xor(os, 4);
  if (kp_lane == 0) op[(size_t)t * CH] = os * 0.08838834764831845f;  // D^-0.5
}

__global__ __launch_bounds__(64) void scan_kernel(
    const bf16_t* __restrict__ qn, const bf16_t* __restrict__ kn,
    const bf16_t* __restrict__ vn, const _Float16* __restrict__ gam,
    const float* __restrict__ beta, float* __restrict__ o) {
  __shared__ _Float16 sg[2][TC][128];  // 8 KiB
  __shared__ bf16_t   sk[2][TC][128];  // 8 KiB
  __shared__ bf16_t   sq[2][TC][128];  // 8 KiB
  __shared__ bf16_t   sv[2][TC][8];    // 512 B (this block's 8 cols)
  __shared__ float    sb[2][TC];

  const int h      = blockIdx.x >> 4;
  const int cg     = blockIdx.x & 15;
  const int tid    = threadIdx.x;
  const int colIdx = tid >> 3;        // 0..7
  const int kp     = tid & 7;
  const int k0     = kp * 16;
  const int lr     = tid >> 4;        // 0..3 (staging row base)
  const int lc     = (tid & 15) * 8;  // staging col

  const _Float16* gbase = gam + (size_t)h * DH;
  const bf16_t*   kbase = kn + (size_t)h * DH;
  const bf16_t*   qbase = qn + (size_t)h * DH;
  const bf16_t*   vbase = vn + (size_t)h * DH + cg * 8;
  const float*    bbase = beta + h;
  float* op = o + (size_t)h * DH + cg * 8 + colIdx;

  auto stage_load = [&](StageR& st, int t0) {
#pragma unroll
    for (int r = 0; r < 4; r++) {
      const size_t go = (size_t)(t0 + lr + r * 4) * CH + lc;
      st.g[r] = *(const uint4*)(gbase + go);
      st.k[r] = *(const uint4*)(kbase + go);
      st.q[r] = *(const uint4*)(qbase + go);
    }
    if (tid < TC) {
      st.v = *(const uint4*)(vbase + (size_t)(t0 + tid) * CH);
      st.b = bbase[(size_t)(t0 + tid) * NH];
    }
  };
  auto stage_store = [&](const StageR& st, int b) {
#pragma unroll
    for (int r = 0; r < 4; r++) {
      *(uint4*)(&sg[b][lr + r * 4][lc]) = st.g[r];
      *(uint4*)(&sk[b][lr + r * 4][lc]) = st.k[r];
      *(uint4*)(&sq[b][lr + r * 4][lc]) = st.q[r];
    }
    if (tid < TC) { *(uint4*)(&sv[b][tid][0]) = st.v; sb[b][tid] = st.b; }
  };
  auto ldstep = [&](StepIn& s, int b, int t) {
    f16x8  g0 = *(const f16x8*)(&sg[b][t][k0]);
    f16x8  g1 = *(const f16x8*)(&sg[b][t][k0 + 8]);
    bf16x8 ka = *(const bf16x8*)(&sk[b][t][k0]);
    bf16x8 kb = *(const bf16x8*)(&sk[b][t][k0 + 8]);
    bf16x8 qa = *(const bf16x8*)(&sq[b][t][k0]);
    bf16x8 qb = *(const bf16x8*)(&sq[b][t][k0 + 8]);
#pragma unroll
    for (int j = 0; j < 8; j++) {
      s.g[j] = (float)g0[j]; s.g[j + 8] = (float)g1[j];
      s.k[j] = (float)ka[j]; s.k[j + 8] = (float)kb[j];
      s.q[j] = (float)qa[j]; s.q[j + 8] = (float)qb[j];
    }
    s.v = (float)sv[b][t][colIdx];
    s.b = sb[b][t];
  };

  float S[16] = {};
  StageR st;
  stage_load(st, 0);
  stage_store(st, 0);
  __syncthreads();

  for (int c = 0; c < NCHK; c++) {
    const int b = c & 1;
    const bool more = (c + 1 < NCHK);
    if (more) stage_load(st, (c + 1) * TC);   // global loads in flight during compute
    StepIn A, B;
    ldstep(A, b, 0);
#pragma unroll
    for (int t = 0; t < TC; t += 2) {
      ldstep(B, b, t + 1);
      dostep(S, A, kp, op, c * TC + t);
      if (t + 2 < TC) ldstep(A, b, t + 2);
      dostep(S, B, kp, op, c * TC + t + 1);
    }
    if (more) stage_store(st, b ^ 1);
    __syncthreads();
  }
}

// ---------------- postprocess: RMSNorm * norm_w * silu(gate bf16) -> bf16 ----------------
__global__ __launch_bounds__(256) void postprocess(
    const float* __restrict__ o, const bf16_t* __restrict__ gate,
    const float* __restrict__ norm_w, bf16_t* __restrict__ og) {
  const int t = blockIdx.x, tid = threadIdx.x;
  const int c0 = tid * 8, d0 = c0 & 127;
  const size_t o0 = (size_t)t * CH + c0;
  float ov[8], gv[8], nw[8];
  { float4 a = *(const float4*)(o + o0);    float4 b = *(const float4*)(o + o0 + 4);
    ov[0]=a.x; ov[1]=a.y; ov[2]=a.z; ov[3]=a.w; ov[4]=b.x; ov[5]=b.y; ov[6]=b.z; ov[7]=b.w;
    bf16x8 g8 = *(const bf16x8*)(gate + o0);
    for (int j = 0; j < 8; j++) gv[j] = (float)g8[j];
    float4 e = *(const float4*)(norm_w + d0); float4 f = *(const float4*)(norm_w + d0 + 4);
    nw[0]=e.x; nw[1]=e.y; nw[2]=e.z; nw[3]=e.w; nw[4]=f.x; nw[5]=f.y; nw[6]=f.z; nw[7]=f.w; }
  float ss = 0.f;
#pragma unroll
  for (int j = 0; j < 8; j++) ss += ov[j] * ov[j];
#pragma unroll
  for (int m = 1; m < 16; m <<= 1) ss += __shfl_xor(ss, m);
  const float rs = rsqrtf(ss * (1.f / 128.f) + 1e-6f);
  bf16x8 r;
#pragma unroll
  for (int j = 0; j < 8; j++) {
    float g = gv[j];
    float val = ov[j] * rs * nw[j] * (g / (1.f + expf(-g)));
    r[j] = (bf16_t)val;
  }
  *(bf16x8*)(og + o0) = r;
}

// ---------------- host launcher ----------------
static inline void launch_gemm(const bf16_t* A, int lda, const bf16_t* Bt, int ldb,
                               void* C, int ldc, int M, int N, int K, bool obf16,
                               hipStream_t s) {
  dim3 grid(M / 128, (N + 127) / 128);
  if (obf16) gemm_bf16<true><<<grid, 256, 0, s>>>(A, lda, Bt, ldb, C, ldc, M, N, K);
  else       gemm_bf16<false><<<grid, 256, 0, s>>>(A, lda, Bt, ldb, C, ldc, M, N, K);
}

extern "C" void kernel_launch(void* const* d_in, const int* in_sizes, int n_in,
                              void* d_out, int out_size, void* d_ws, size_t ws_size,
                              hipStream_t stream) {
  const float* x       = (const float*)d_in[0];
  const float* Wq      = (const float*)d_in[1];
  const float* Wk      = (const float*)d_in[2];
  const float* Wv      = (const float*)d_in[3];
  const float* wqc     = (const float*)d_in[4];
  const float* wkc     = (const float*)d_in[5];
  const float* wvc     = (const float*)d_in[6];
  const float* A_log   = (const float*)d_in[7];
  const float* dt_bias = (const float*)d_in[8];
  const float* Wfa     = (const float*)d_in[9];
  const float* Wfb     = (const float*)d_in[10];
  const float* Wb      = (const float*)d_in[11];
  const float* Wga     = (const float*)d_in[12];
  const float* Wgb     = (const float*)d_in[13];
  const float* norm_w  = (const float*)d_in[14];
  const float* Wo      = (const float*)d_in[15];

  char* w = (char*)d_ws;
  size_t off = 0;
  auto give = [&](size_t bytes) -> void* {
    size_t cur = off;
    off = (off + bytes + 255) & ~(size_t)255;
    return (void*)(w + cur);
  };
  // peak workspace ~130 MiB
  bf16_t* Wbig = (bf16_t*)give((size_t)CH * HID * 2);   // reused: WqT,WkT,WvT,WoT
  bf16_t* WfaT = (bf16_t*)give((size_t)128 * HID * 2);
  bf16_t* WgaT = (bf16_t*)give((size_t)128 * HID * 2);
  bf16_t* WfbT = (bf16_t*)give((size_t)CH * 128 * 2);
  bf16_t* WgbT = (bf16_t*)give((size_t)CH * 128 * 2);
  bf16_t* WbT  = (bf16_t*)give((size_t)NH * HID * 2);
  bf16_t* Ax   = (bf16_t*)give((size_t)T_TOK * HID * 2);  // 16 MiB
  bf16_t* raw0 = (bf16_t*)give((size_t)T_TOK * CH * 2);   // 16 MiB, reused q/k/v raw
  bf16_t* qnb  = (bf16_t*)give((size_t)T_TOK * CH * 2);
  bf16_t* knb  = (bf16_t*)give((size_t)T_TOK * CH * 2);
  bf16_t* vnb  = (bf16_t*)give((size_t)T_TOK * CH * 2);
  bf16_t* f1b  = (bf16_t*)give((size_t)T_TOK * 128 * 2);
  bf16_t* g1b  = (bf16_t*)give((size_t)T_TOK * 128 * 2);
  float*  fbuf = (float*)give((size_t)T_TOK * CH * 4);    // f_pre (fp32)
  _Float16* ghalf = (_Float16*)give((size_t)T_TOK * CH * 2);  // gamma fp16
  bf16_t* gateb= (bf16_t*)give((size_t)T_TOK * CH * 2);
  float*  betab= (float*)give((size_t)T_TOK * NH * 4);
  // aliases over dead regions:
  float*  obuf = (float*)Ax;    // 32 MiB = Ax(16)+raw0(16), both dead before scan
  bf16_t* ogb  = qnb;           // qnb dead after scan

  auto tr = [&](const float* in, bf16_t* out, int R, int C) {
    transpose_cast<<<dim3((R + 31) / 32, (C + 31) / 32), 256, 0, stream>>>(in, out, R, C);
  };

  // 1) cast x, small weight transposes
  cast_to_bf16<<<dim3((T_TOK * HID) / 2048), 256, 0, stream>>>(x, Ax, T_TOK * HID);
  tr(Wfa, WfaT, HID, 128); tr(Wga, WgaT, HID, 128);
  tr(Wfb, WfbT, 128, CH);  tr(Wgb, WgbT, 128, CH);
  tr(Wb, WbT, HID, NH);

  // 2) q/k/v: transpose weight -> GEMM -> conv+silu(+l2norm), reusing Wbig and raw0
  tr(Wq, Wbig, HID, CH);
  launch_gemm(Ax, HID, Wbig, HID, raw0, CH, T_TOK, CH, HID, true, stream);
  conv_silu<true><<<dim3(T_TOK), 256, 0, stream>>>(raw0, wqc, qnb);
  tr(Wk, Wbig, HID, CH);
  launch_gemm(Ax, HID, Wbig, HID, raw0, CH, T_TOK, CH, HID, true, stream);
  conv_silu<true><<<dim3(T_TOK), 256, 0, stream>>>(raw0, wkc, knb);
  tr(Wv, Wbig, HID, CH);
  launch_gemm(Ax, HID, Wbig, HID, raw0, CH, T_TOK, CH, HID, true, stream);
  conv_silu<false><<<dim3(T_TOK), 256, 0, stream>>>(raw0, wvc, vnb);

  // 3) f/g/beta chains
  launch_gemm(Ax, HID, WfaT, HID, f1b, 128, T_TOK, 128, HID, true, stream);
  launch_gemm(Ax, HID, WgaT, HID, g1b, 128, T_TOK, 128, HID, true, stream);
  launch_gemm(Ax, HID, WbT, HID, betab, NH, T_TOK, NH, HID, false, stream);
  launch_gemm(f1b, 128, WfbT, 128, fbuf, CH, T_TOK, CH, 128, false, stream);
  launch_gemm(g1b, 128, WgbT, 128, gateb, CH, T_TOK, CH, 128, true, stream);
  gamma_beta<<<dim3(T_TOK), 256, 0, stream>>>(fbuf, dt_bias, A_log, ghalf, betab);

  // 4) sequential delta-rule scan: 256 blocks x 64 threads (1 wave/CU)
  scan_kernel<<<dim3(256), 64, 0, stream>>>(qnb, knb, vnb, ghalf, betab, obuf);

  // 5) gated RMSNorm -> bf16 (ogb aliases qnb)
  postprocess<<<dim3(T_TOK), 256, 0, stream>>>(obuf, gateb, norm_w, ogb);

  // 6) output projection
  tr(Wo, Wbig, CH, HID);
  launch_gemm(ogb, CH, Wbig, CH, (float*)d_out, HID, T_TOK, HID, CH, false, stream);
}

// Round 5
// 1828.432 us; speedup vs baseline: 1.4848x; 1.4848x over previous
//
#include <hip/hip_runtime.h>
#include <hip/hip_bf16.h>
#include <math.h>

typedef __bf16 bf16_t;
typedef __bf16 bf16x8 __attribute__((ext_vector_type(8)));
typedef float  floatx4 __attribute__((ext_vector_type(4)));

constexpr int T_TOK = 4096;
constexpr int HID   = 2048;
constexpr int NH    = 16;
constexpr int DH    = 128;   // head dim
constexpr int CH    = 2048;  // NH*DH

// ---------------- cast fp32 -> bf16 (row-major preserved) ----------------
__global__ __launch_bounds__(256) void cast_to_bf16(const float* __restrict__ in,
                                                    bf16_t* __restrict__ out, int n) {
  int i = (blockIdx.x * 256 + threadIdx.x) * 8;
  if (i >= n) return;
  float4 a = *(const float4*)(in + i);
  float4 b = *(const float4*)(in + i + 4);
  bf16x8 o;
  o[0]=(bf16_t)a.x; o[1]=(bf16_t)a.y; o[2]=(bf16_t)a.z; o[3]=(bf16_t)a.w;
  o[4]=(bf16_t)b.x; o[5]=(bf16_t)b.y; o[6]=(bf16_t)b.z; o[7]=(bf16_t)b.w;
  *(bf16x8*)(out + i) = o;
}

// ---------------- transpose + cast: in fp32 [R,C] -> out bf16 [C,R] ----------------
__global__ __launch_bounds__(256) void transpose_cast(const float* __restrict__ in,
                                                      bf16_t* __restrict__ out, int R, int C) {
  __shared__ float tile[32][33];
  int tx = threadIdx.x & 31;
  int ty = threadIdx.x >> 5;  // 0..7
  int r0 = blockIdx.x * 32;
  int c0 = blockIdx.y * 32;
#pragma unroll
  for (int i = 0; i < 4; i++) {
    int r = ty + i * 8;
    float v = 0.f;
    if (r0 + r < R && c0 + tx < C) v = in[(size_t)(r0 + r) * C + (c0 + tx)];
    tile[r][tx] = v;
  }
  __syncthreads();
#pragma unroll
  for (int i = 0; i < 4; i++) {
    int cr = ty + i * 8;
    if (c0 + cr < C && r0 + tx < R)
      out[(size_t)(c0 + cr) * R + (r0 + tx)] = (bf16_t)tile[tx][cr];
  }
}

// ---------------- bf16 MFMA GEMM: C[M,N] = A[M,K] * Bt[N,K]^T ----------------
template<bool OUT_BF16>
__global__ __launch_bounds__(256) void gemm_bf16(
    const bf16_t* __restrict__ A, int lda,
    const bf16_t* __restrict__ Bt, int ldb,
    void* __restrict__ Cv, int ldc, int M, int N, int K) {
  __shared__ bf16_t sA[128][40];
  __shared__ bf16_t sB[128][40];
  const int tid  = threadIdx.x;
  const int bm0  = blockIdx.x * 128;
  const int bn0  = blockIdx.y * 128;
  const int wave = tid >> 6;
  const int lane = tid & 63;
  const int wm   = (wave & 1) * 64;
  const int wn   = (wave >> 1) * 64;
  const int fm   = lane & 15;
  const int kq   = lane >> 4;

  floatx4 acc[4][4];
#pragma unroll
  for (int mi = 0; mi < 4; mi++)
#pragma unroll
    for (int ni = 0; ni < 4; ni++)
      acc[mi][ni] = (floatx4){0.f, 0.f, 0.f, 0.f};

  const int sr = tid >> 2;
  const int sk = (tid & 3) * 8;
  const bool bval0 = (bn0 + sr) < N;
  const bool bval1 = (bn0 + sr + 64) < N;
  const bf16_t* Ag0 = A + (size_t)(bm0 + sr) * lda + sk;
  const bf16_t* Ag1 = Ag0 + (size_t)64 * lda;
  const bf16_t* Bg0 = Bt + (size_t)(bn0 + sr) * ldb + sk;
  const bf16_t* Bg1 = Bg0 + (size_t)64 * ldb;

  for (int k0 = 0; k0 < K; k0 += 32) {
    float4 a0 = *(const float4*)(Ag0 + k0);
    float4 a1 = *(const float4*)(Ag1 + k0);
    float4 b0 = bval0 ? *(const float4*)(Bg0 + k0) : make_float4(0.f, 0.f, 0.f, 0.f);
    float4 b1 = bval1 ? *(const float4*)(Bg1 + k0) : make_float4(0.f, 0.f, 0.f, 0.f);
    __syncthreads();
    *(float4*)(&sA[sr][sk])      = a0;
    *(float4*)(&sA[sr + 64][sk]) = a1;
    *(float4*)(&sB[sr][sk])      = b0;
    *(float4*)(&sB[sr + 64][sk]) = b1;
    __syncthreads();
    bf16x8 afr[4], bfr[4];
#pragma unroll
    for (int i = 0; i < 4; i++) {
      afr[i] = *(const bf16x8*)(&sA[wm + i * 16 + fm][kq * 8]);
      bfr[i] = *(const bf16x8*)(&sB[wn + i * 16 + fm][kq * 8]);
    }
#pragma unroll
    for (int mi = 0; mi < 4; mi++)
#pragma unroll
      for (int ni = 0; ni < 4; ni++)
        acc[mi][ni] = __builtin_amdgcn_mfma_f32_16x16x32_bf16(afr[mi], bfr[ni], acc[mi][ni], 0, 0, 0);
  }

  const int rr = (lane >> 4) * 4;
#pragma unroll
  for (int mi = 0; mi < 4; mi++) {
#pragma unroll
    for (int r = 0; r < 4; r++) {
      const int row = bm0 + wm + mi * 16 + rr + r;
#pragma unroll
      for (int ni = 0; ni < 4; ni++) {
        const int col = bn0 + wn + ni * 16 + fm;
        if (col < N) {
          if constexpr (OUT_BF16)
            ((bf16_t*)Cv)[(size_t)row * ldc + col] = (bf16_t)acc[mi][ni][r];
          else
            ((float*)Cv)[(size_t)row * ldc + col] = acc[mi][ni][r];
        }
      }
    }
  }
}

// ---------------- conv + silu (+ l2norm) : raw bf16 [T,CH] -> out bf16 [T,CH] ----------------
template<bool L2NORM>
__global__ __launch_bounds__(256) void conv_silu(
    const bf16_t* __restrict__ raw, const float* __restrict__ wconv,
    bf16_t* __restrict__ out) {
  const int t   = blockIdx.x;
  const int tid = threadIdx.x;
  const int c0  = tid * 8;

  float w[8][4];
#pragma unroll
  for (int j = 0; j < 8; j++) {
    float4 t0 = *(const float4*)(wconv + (size_t)(c0 + j) * 4);
    w[j][0] = t0.x; w[j][1] = t0.y; w[j][2] = t0.z; w[j][3] = t0.w;
  }
  float a[8] = {};
#pragma unroll
  for (int i = 0; i < 4; i++) {
    int tr = t - 3 + i;
    if (tr < 0) continue;
    bf16x8 xr = *(const bf16x8*)(raw + (size_t)tr * CH + c0);
#pragma unroll
    for (int j = 0; j < 8; j++) a[j] += w[j][i] * (float)xr[j];
  }
  float s = 0.f;
#pragma unroll
  for (int j = 0; j < 8; j++) {
    a[j] = a[j] / (1.f + expf(-a[j]));  // silu
    s += a[j] * a[j];
  }
  float rs = 1.f;
  if constexpr (L2NORM) {
#pragma unroll
    for (int m = 1; m < 16; m <<= 1) s += __shfl_xor(s, m);
    rs = rsqrtf(s + 1e-6f);
  }
  bf16x8 r;
#pragma unroll
  for (int j = 0; j < 8; j++) r[j] = (bf16_t)(a[j] * rs);
  *(bf16x8*)(out + (size_t)t * CH + c0) = r;
}

// ---------------- gamma (in-place fp32 over f_pre) + beta sigmoid (in-place) ----------------
__global__ __launch_bounds__(256) void gamma_beta(
    float* __restrict__ f_gam, const float* __restrict__ dt_bias,
    const float* __restrict__ A_log, float* __restrict__ beta_io) {
  const int t   = blockIdx.x;
  const int tid = threadIdx.x;
  const int c0  = tid * 8;
  const int h   = c0 >> 7;
  const float a_h = expf(A_log[h]);
  const size_t o0 = (size_t)t * CH + c0;
  float fv[8], db[8];
  { float4 f0 = *(const float4*)(f_gam + o0);   float4 f1 = *(const float4*)(f_gam + o0 + 4);
    fv[0]=f0.x; fv[1]=f0.y; fv[2]=f0.z; fv[3]=f0.w; fv[4]=f1.x; fv[5]=f1.y; fv[6]=f1.z; fv[7]=f1.w;
    float4 d0 = *(const float4*)(dt_bias + c0); float4 d1 = *(const float4*)(dt_bias + c0 + 4);
    db[0]=d0.x; db[1]=d0.y; db[2]=d0.z; db[3]=d0.w; db[4]=d1.x; db[5]=d1.y; db[6]=d1.z; db[7]=d1.w; }
  float og[8];
#pragma unroll
  for (int j = 0; j < 8; j++) {
    float f = fv[j] + db[j];
    float sp = (f > 20.f) ? f : log1pf(expf(f));
    og[j] = expf(-a_h * sp);
  }
  *(float4*)(f_gam + o0)     = make_float4(og[0], og[1], og[2], og[3]);
  *(float4*)(f_gam + o0 + 4) = make_float4(og[4], og[5], og[6], og[7]);
  if (tid < NH) {
    float b = beta_io[(size_t)t * NH + tid];
    beta_io[(size_t)t * NH + tid] = 1.f / (1.f + expf(-b));
  }
}

// ---------------- sequential scan (DPP reductions, 16 lanes/col) ----------------
// 512 blocks = (head, 4-col group); 64 threads = 1 wave. 16 lanes per column,
// 8 k-states per lane. Reductions over 16 lanes via DPP (VALU-speed, no LDS):
// xor1 = quad_perm(1,0,3,2)=0xB1; xor2 = quad_perm(2,3,0,1)=0x4E;
// then row_half_mirror (0x141) and row_mirror (0x140) — valid because values
// are quad-uniform / half-row-uniform after the earlier stages.
constexpr int TC   = 16;
constexpr int NCHK = T_TOK / TC;
constexpr int COLS = 4;

template<int CTRL>
__device__ __forceinline__ float dpp_add(float x) {
  int v = __builtin_amdgcn_update_dpp(0, __builtin_bit_cast(int, x), CTRL, 0xF, 0xF, true);
  return x + __builtin_bit_cast(float, v);
}
__device__ __forceinline__ float red16(float x) {
  x = dpp_add<0xB1>(x);    // xor1
  x = dpp_add<0x4E>(x);    // xor2
  x = dpp_add<0x141>(x);   // row_half_mirror == xor4 (quad-uniform)
  x = dpp_add<0x140>(x);   // row_mirror == xor8 (half-row-uniform)
  return x;
}
__device__ __forceinline__ void bf2f(unsigned u, float& lo, float& hi) {
  lo = __builtin_bit_cast(float, u << 16);
  hi = __builtin_bit_cast(float, u & 0xFFFF0000u);
}

struct StageR { uint4 g[8]; uint4 k[4]; uint4 q[4]; uint2 v; float b; };

__global__ __launch_bounds__(64) void scan_kernel(
    const bf16_t* __restrict__ qn, const bf16_t* __restrict__ kn,
    const bf16_t* __restrict__ vn, const float* __restrict__ gam,
    const float* __restrict__ beta, float* __restrict__ o) {
  __shared__ float  sg[2][TC][128];    // 16 KiB
  __shared__ bf16_t sk[2][TC][128];    // 8 KiB
  __shared__ bf16_t sq[2][TC][128];    // 8 KiB
  __shared__ bf16_t sv[2][TC][COLS];   // 256 B
  __shared__ float  sb[2][TC];

  const int h      = blockIdx.x >> 5;   // 16 heads
  const int cg     = blockIdx.x & 31;   // 32 col-groups
  const int tid    = threadIdx.x;
  const int colIdx = tid >> 4;          // 0..3
  const int kp     = tid & 15;          // k-partition
  const int k0     = kp * 8;

  const float*  gbase = gam + (size_t)h * DH;
  const bf16_t* kbase = kn + (size_t)h * DH;
  const bf16_t* qbase = qn + (size_t)h * DH;
  const bf16_t* vbase = vn + (size_t)h * DH + cg * COLS;
  const float*  bbase = beta + h;
  float* op = o + (size_t)h * DH + cg * COLS + colIdx;

  auto stage_load = [&](StageR& st, int t0) {
#pragma unroll
    for (int r = 0; r < 8; r++) {       // gamma fp32: TC*128*4B = 8KB
      int idx = r * 64 + tid;
      st.g[r] = *(const uint4*)(gbase + (size_t)(t0 + (idx >> 5)) * CH + (idx & 31) * 4);
    }
#pragma unroll
    for (int r = 0; r < 4; r++) {       // k/q bf16: TC*128*2B = 4KB each
      int idx = r * 64 + tid;
      const size_t go = (size_t)(t0 + (idx >> 4)) * CH + (idx & 15) * 8;
      st.k[r] = *(const uint4*)(kbase + go);
      st.q[r] = *(const uint4*)(qbase + go);
    }
    if (tid < TC) {
      st.v = *(const uint2*)(vbase + (size_t)(t0 + tid) * CH);
      st.b = bbase[(size_t)(t0 + tid) * NH];
    }
  };
  auto stage_store = [&](const StageR& st, int b) {
#pragma unroll
    for (int r = 0; r < 8; r++) {
      int idx = r * 64 + tid;
      *(uint4*)(&sg[b][idx >> 5][(idx & 31) * 4]) = st.g[r];
    }
#pragma unroll
    for (int r = 0; r < 4; r++) {
      int idx = r * 64 + tid;
      *(uint4*)(&sk[b][idx >> 4][(idx & 15) * 8]) = st.k[r];
      *(uint4*)(&sq[b][idx >> 4][(idx & 15) * 8]) = st.q[r];
    }
    if (tid < TC) { *(uint2*)(&sv[b][tid][0]) = st.v; sb[b][tid] = st.b; }
  };

  struct StepIn { float g[8], k[8], q[8], v, b; };
  auto ldstep = [&](StepIn& s, int b, int t) {
    float4 g0 = *(const float4*)(&sg[b][t][k0]);
    float4 g1 = *(const float4*)(&sg[b][t][k0 + 4]);
    s.g[0]=g0.x; s.g[1]=g0.y; s.g[2]=g0.z; s.g[3]=g0.w;
    s.g[4]=g1.x; s.g[5]=g1.y; s.g[6]=g1.z; s.g[7]=g1.w;
    uint4 kw = *(const uint4*)(&sk[b][t][k0]);
    uint4 qw = *(const uint4*)(&sq[b][t][k0]);
    bf2f(kw.x, s.k[0], s.k[1]); bf2f(kw.y, s.k[2], s.k[3]);
    bf2f(kw.z, s.k[4], s.k[5]); bf2f(kw.w, s.k[6], s.k[7]);
    bf2f(qw.x, s.q[0], s.q[1]); bf2f(qw.y, s.q[2], s.q[3]);
    bf2f(qw.z, s.q[4], s.q[5]); bf2f(qw.w, s.q[6], s.q[7]);
    s.v = (float)sv[b][t][colIdx];
    s.b = sb[b][t];
  };

  float S[8] = {};
  auto dostep = [&](const StepIn& in, int t) {
    float e0 = 0.f, e1 = 0.f, e2 = 0.f, e3 = 0.f;
#pragma unroll
    for (int j = 0; j < 2; j++) {
      S[j]     *= in.g[j];     e0 = fmaf(S[j],     in.k[j],     e0);
      S[j + 2] *= in.g[j + 2]; e1 = fmaf(S[j + 2], in.k[j + 2], e1);
      S[j + 4] *= in.g[j + 4]; e2 = fmaf(S[j + 4], in.k[j + 4], e2);
      S[j + 6] *= in.g[j + 6]; e3 = fmaf(S[j + 6], in.k[j + 6], e3);
    }
    float err = red16((e0 + e1) + (e2 + e3));
    const float dv = in.b * (in.v - err);
    float o0 = 0.f, o1 = 0.f, o2 = 0.f, o3 = 0.f;
#pragma unroll
    for (int j = 0; j < 2; j++) {
      S[j]     = fmaf(in.k[j],     dv, S[j]);     o0 = fmaf(S[j],     in.q[j],     o0);
      S[j + 2] = fmaf(in.k[j + 2], dv, S[j + 2]); o1 = fmaf(S[j + 2], in.q[j + 2], o1);
      S[j + 4] = fmaf(in.k[j + 4], dv, S[j + 4]); o2 = fmaf(S[j + 4], in.q[j + 4], o2);
      S[j + 6] = fmaf(in.k[j + 6], dv, S[j + 6]); o3 = fmaf(S[j + 6], in.q[j + 6], o3);
    }
    float os = red16((o0 + o1) + (o2 + o3));
    if (kp == 0) op[(size_t)t * CH] = os * 0.08838834764831845f;  // D^-0.5
  };

  StageR st;
  stage_load(st, 0);
  stage_store(st, 0);
  __syncthreads();

  for (int c = 0; c < NCHK; c++) {
    const int b = c & 1;
    const bool more = (c + 1 < NCHK);
    if (more) stage_load(st, (c + 1) * TC);   // global loads in flight during compute
    StepIn A, B;
    ldstep(A, b, 0);
#pragma unroll
    for (int t = 0; t < TC; t += 2) {
      ldstep(B, b, t + 1);
      dostep(A, c * TC + t);
      if (t + 2 < TC) ldstep(A, b, t + 2);
      dostep(B, c * TC + t + 1);
    }
    if (more) stage_store(st, b ^ 1);
    __syncthreads();
  }
}

// ---------------- postprocess: RMSNorm * norm_w * silu(gate bf16) -> bf16 ----------------
__global__ __launch_bounds__(256) void postprocess(
    const float* __restrict__ o, const bf16_t* __restrict__ gate,
    const float* __restrict__ norm_w, bf16_t* __restrict__ og) {
  const int t = blockIdx.x, tid = threadIdx.x;
  const int c0 = tid * 8, d0 = c0 & 127;
  const size_t o0 = (size_t)t * CH + c0;
  float ov[8], gv[8], nw[8];
  { float4 a = *(const float4*)(o + o0);    float4 b = *(const float4*)(o + o0 + 4);
    ov[0]=a.x; ov[1]=a.y; ov[2]=a.z; ov[3]=a.w; ov[4]=b.x; ov[5]=b.y; ov[6]=b.z; ov[7]=b.w;
    bf16x8 g8 = *(const bf16x8*)(gate + o0);
    for (int j = 0; j < 8; j++) gv[j] = (float)g8[j];
    float4 e = *(const float4*)(norm_w + d0); float4 f = *(const float4*)(norm_w + d0 + 4);
    nw[0]=e.x; nw[1]=e.y; nw[2]=e.z; nw[3]=e.w; nw[4]=f.x; nw[5]=f.y; nw[6]=f.z; nw[7]=f.w; }
  float ss = 0.f;
#pragma unroll
  for (int j = 0; j < 8; j++) ss += ov[j] * ov[j];
#pragma unroll
  for (int m = 1; m < 16; m <<= 1) ss += __shfl_xor(ss, m);
  const float rs = rsqrtf(ss * (1.f / 128.f) + 1e-6f);
  bf16x8 r;
#pragma unroll
  for (int j = 0; j < 8; j++) {
    float g = gv[j];
    float val = ov[j] * rs * nw[j] * (g / (1.f + expf(-g)));
    r[j] = (bf16_t)val;
  }
  *(bf16x8*)(og + o0) = r;
}

// ---------------- host launcher ----------------
static inline void launch_gemm(const bf16_t* A, int lda, const bf16_t* Bt, int ldb,
                               void* C, int ldc, int M, int N, int K, bool obf16,
                               hipStream_t s) {
  dim3 grid(M / 128, (N + 127) / 128);
  if (obf16) gemm_bf16<true><<<grid, 256, 0, s>>>(A, lda, Bt, ldb, C, ldc, M, N, K);
  else       gemm_bf16<false><<<grid, 256, 0, s>>>(A, lda, Bt, ldb, C, ldc, M, N, K);
}

extern "C" void kernel_launch(void* const* d_in, const int* in_sizes, int n_in,
                              void* d_out, int out_size, void* d_ws, size_t ws_size,
                              hipStream_t stream) {
  const float* x       = (const float*)d_in[0];
  const float* Wq      = (const float*)d_in[1];
  const float* Wk      = (const float*)d_in[2];
  const float* Wv      = (const float*)d_in[3];
  const float* wqc     = (const float*)d_in[4];
  const float* wkc     = (const float*)d_in[5];
  const float* wvc     = (const float*)d_in[6];
  const float* A_log   = (const float*)d_in[7];
  const float* dt_bias = (const float*)d_in[8];
  const float* Wfa     = (const float*)d_in[9];
  const float* Wfb     = (const float*)d_in[10];
  const float* Wb      = (const float*)d_in[11];
  const float* Wga     = (const float*)d_in[12];
  const float* Wgb     = (const float*)d_in[13];
  const float* norm_w  = (const float*)d_in[14];
  const float* Wo      = (const float*)d_in[15];

  char* w = (char*)d_ws;
  size_t off = 0;
  auto give = [&](size_t bytes) -> void* {
    size_t cur = off;
    off = (off + bytes + 255) & ~(size_t)255;
    return (void*)(w + cur);
  };
  // peak workspace ~128 MiB
  bf16_t* Wbig = (bf16_t*)give((size_t)CH * HID * 2);   // reused: WqT,WkT,WvT,WoT
  bf16_t* WfaT = (bf16_t*)give((size_t)128 * HID * 2);
  bf16_t* WgaT = (bf16_t*)give((size_t)128 * HID * 2);
  bf16_t* WfbT = (bf16_t*)give((size_t)CH * 128 * 2);
  bf16_t* WgbT = (bf16_t*)give((size_t)CH * 128 * 2);
  bf16_t* WbT  = (bf16_t*)give((size_t)NH * HID * 2);
  bf16_t* Ax   = (bf16_t*)give((size_t)T_TOK * HID * 2);  // 16 MiB
  bf16_t* raw0 = (bf16_t*)give((size_t)T_TOK * CH * 2);   // 16 MiB, reused q/k/v raw
  bf16_t* qnb  = (bf16_t*)give((size_t)T_TOK * CH * 2);
  bf16_t* knb  = (bf16_t*)give((size_t)T_TOK * CH * 2);
  bf16_t* vnb  = (bf16_t*)give((size_t)T_TOK * CH * 2);
  bf16_t* f1b  = (bf16_t*)give((size_t)T_TOK * 128 * 2);
  bf16_t* g1b  = (bf16_t*)give((size_t)T_TOK * 128 * 2);
  float*  fbuf = (float*)give((size_t)T_TOK * CH * 4);    // f_pre -> gamma fp32 in-place
  bf16_t* gateb= (bf16_t*)give((size_t)T_TOK * CH * 2);
  float*  betab= (float*)give((size_t)T_TOK * NH * 4);
  // aliases over dead regions:
  float*  obuf = (float*)Ax;    // 32 MiB = Ax(16)+raw0(16), both dead before scan
  bf16_t* ogb  = qnb;           // qnb dead after scan

  auto tr = [&](const float* in, bf16_t* out, int R, int C) {
    transpose_cast<<<dim3((R + 31) / 32, (C + 31) / 32), 256, 0, stream>>>(in, out, R, C);
  };

  // 1) cast x, small weight transposes
  cast_to_bf16<<<dim3((T_TOK * HID) / 2048), 256, 0, stream>>>(x, Ax, T_TOK * HID);
  tr(Wfa, WfaT, HID, 128); tr(Wga, WgaT, HID, 128);
  tr(Wfb, WfbT, 128, CH);  tr(Wgb, WgbT, 128, CH);
  tr(Wb, WbT, HID, NH);

  // 2) q/k/v: transpose weight -> GEMM -> conv+silu(+l2norm), reusing Wbig and raw0
  tr(Wq, Wbig, HID, CH);
  launch_gemm(Ax, HID, Wbig, HID, raw0, CH, T_TOK, CH, HID, true, stream);
  conv_silu<true><<<dim3(T_TOK), 256, 0, stream>>>(raw0, wqc, qnb);
  tr(Wk, Wbig, HID, CH);
  launch_gemm(Ax, HID, Wbig, HID, raw0, CH, T_TOK, CH, HID, true, stream);
  conv_silu<true><<<dim3(T_TOK), 256, 0, stream>>>(raw0, wkc, knb);
  tr(Wv, Wbig, HID, CH);
  launch_gemm(Ax, HID, Wbig, HID, raw0, CH, T_TOK, CH, HID, true, stream);
  conv_silu<false><<<dim3(T_TOK), 256, 0, stream>>>(raw0, wvc, vnb);

  // 3) f/g/beta chains
  launch_gemm(Ax, HID, WfaT, HID, f1b, 128, T_TOK, 128, HID, true, stream);
  launch_gemm(Ax, HID, WgaT, HID, g1b, 128, T_TOK, 128, HID, true, stream);
  launch_gemm(Ax, HID, WbT, HID, betab, NH, T_TOK, NH, HID, false, stream);
  launch_gemm(f1b, 128, WfbT, 128, fbuf, CH, T_TOK, CH, 128, false, stream);
  launch_gemm(g1b, 128, WgbT, 128, gateb, CH, T_TOK, CH, 128, true, stream);
  gamma_beta<<<dim3(T_TOK), 256, 0, stream>>>(fbuf, dt_bias, A_log, betab);

  // 4) sequential delta-rule scan: 512 blocks x 64 threads, DPP reductions
  scan_kernel<<<dim3(512), 64, 0, stream>>>(qnb, knb, vnb, fbuf, betab, obuf);

  // 5) gated RMSNorm -> bf16 (ogb aliases qnb)
  postprocess<<<dim3(T_TOK), 256, 0, stream>>>(obuf, gateb, norm_w, ogb);

  // 6) output projection
  tr(Wo, Wbig, CH, HID);
  launch_gemm(ogb, CH, Wbig, CH, (float*)d_out, HID, T_TOK, HID, CH, false, stream);
}